// Round 8
// baseline (780.621 us; speedup 1.0000x reference)
//
#include <hip/hip_runtime.h>

typedef unsigned short us;
typedef __bf16 v8bf __attribute__((ext_vector_type(8)));
typedef float v4f __attribute__((ext_vector_type(4)));
typedef us us4v __attribute__((ext_vector_type(4)));
typedef us us8v __attribute__((ext_vector_type(8)));
typedef float f4v __attribute__((ext_vector_type(4)));

#define SCALE 0.08838834764831845f

__device__ __forceinline__ us f2bf(float f) {
  unsigned u = __builtin_bit_cast(unsigned, f);
  u += 0x7fffu + ((u >> 16) & 1u);
  return (us)(u >> 16);
}
__device__ __forceinline__ float bf2f(us h) {
  unsigned u = ((unsigned)h) << 16;
  return __builtin_bit_cast(float, u);
}

typedef const __attribute__((address_space(1))) void* gas_t;
typedef __attribute__((address_space(3))) void* las_t;
#define GLD16(gp, lp) __builtin_amdgcn_global_load_lds((gas_t)(gp), (las_t)(lp), 16, 0, 0)

// ---------------- fp32 -> bf16 casts ----------------
__global__ void cast_kernel(const float* __restrict__ in, us* __restrict__ out, int n) {
  int stride = gridDim.x * blockDim.x * 4;
  for (int i = (blockIdx.x * blockDim.x + threadIdx.x) * 4; i < n; i += stride) {
    f4v f = *(const f4v*)(in + i);
    us4v o;
#pragma unroll
    for (int j = 0; j < 4; ++j) o[j] = f2bf(f[j]);
    *(us4v*)(out + i) = o;
  }
}

__global__ void cast2_kernel(const float* __restrict__ a, us* __restrict__ oa, int na,
                             const float* __restrict__ b, us* __restrict__ ob, int nb) {
  int total = na + nb;
  int stride = gridDim.x * blockDim.x * 4;
  for (int i = (blockIdx.x * blockDim.x + threadIdx.x) * 4; i < total; i += stride) {
    const float* s = (i < na) ? (a + i) : (b + (i - na));
    us* d = (i < na) ? (oa + i) : (ob + (i - na));
    f4v f = *(const f4v*)s;
    us4v o;
#pragma unroll
    for (int j = 0; j < 4; ++j) o[j] = f2bf(f[j]);
    *(us4v*)d = o;
  }
}

// ---------------- 256x256 GEMM, 2-barriers-per-TILE schedule ----------------
// R8: dissolve the 8-phase lockstep. Per K-tile: 4 MFMA quadrant clusters with
// the next cluster's ds_reads pinned between them (sched_barrier only, NO
// intra-tile s_barrier, NO asm lgkm -> compiler emits partial waits; WAR reuse
// of af[] is HW-scoreboard-safe). Tile sync block: barrier#1 (all waves done
// reading buf p) -> stage 8 GLDs (t+2 -> buf p) -> vmcnt(8) (t+1's loads,
// issued one full tile ago, have landed; t+2's stay in flight) -> barrier#2
// (buf p^1 now valid) -> read tile t+1's first-quadrant frags.
// Waves drift freely between barriers -> LDS pipe and MFMA pipe overlap
// across the 8 waves instead of serializing in lockstep windows.
template <int EPI>
__global__ __launch_bounds__(512, 2) void gemm8(
    const us* __restrict__ A, const us* __restrict__ Bt, int M, int N, int K,
    float* __restrict__ outF, us* __restrict__ outQ, us* __restrict__ outK,
    us* __restrict__ outV, const float* __restrict__ cosT,
    const float* __restrict__ sinT, int MT) {
  __shared__ us lds[65536];  // buf0: A[0,16384) B[16384,32768); buf1: +32768
  const int tid = threadIdx.x, lane = tid & 63, w = tid >> 6;
  const int nwg = gridDim.x;
  const int bid = blockIdx.x;
  const int cpx = nwg >> 3;
  const int swz = (bid & 7) * cpx + (bid >> 3);  // grids %8==0 (768, 256)
  const int bm = swz % MT, bn = swz / MT;
  const int row0 = bm * 256, col0 = bn * 256;
  const int wr = w >> 2, wc = w & 3;
  const int lr = lane & 15, lg = lane >> 4;
  const int NTK = K >> 6;  // even (64)

#define STAGE_A(t, p, j)                                                      \
  do {                                                                        \
    int q_ = (j) * 512 + tid;                                                 \
    int row_ = q_ >> 3, cph_ = q_ & 7;                                        \
    GLD16(A + (long)(row0 + row_) * K + (t) * 64 + ((cph_ ^ (row_ & 7)) * 8), \
          &lds[(p) * 32768 + ((j) * 512 + w * 64) * 8]);                      \
  } while (0)
#define STAGE_B(t, p, j)                                                      \
  do {                                                                        \
    int q_ = (j) * 512 + tid;                                                 \
    int row_ = q_ >> 3, cph_ = q_ & 7;                                        \
    GLD16(Bt + (long)(col0 + row_) * K + (t) * 64 + ((cph_ ^ (row_ & 7)) * 8),\
          &lds[(p) * 32768 + 16384 + ((j) * 512 + w * 64) * 8]);              \
  } while (0)

  // wave fragment n -> B-row / C-col remap (RoPE partner d<->d+64 = n^2)
#define COLREL(n) (((wc) >> 1) * 128 + ((n) >> 1) * 64 + ((wc) & 1) * 32 + ((n) & 1) * 16)

// swizzled fragment load (row&7 == lr&7 for all rows we touch)
#define LDF(base, row, kkv) \
  (*(const v8bf*)&(base)[(row) * 64 + (((((kkv) * 4) + lg) ^ ((row) & 7)) * 8)])

#define RD_ALO(base)                                                          \
  af[0][0] = LDF(base, ar0, 0); af[1][0] = LDF(base, ar0 + 16, 0);            \
  af[2][0] = LDF(base, ar0 + 32, 0); af[3][0] = LDF(base, ar0 + 48, 0);       \
  af[0][1] = LDF(base, ar0, 1); af[1][1] = LDF(base, ar0 + 16, 1);            \
  af[2][1] = LDF(base, ar0 + 32, 1); af[3][1] = LDF(base, ar0 + 48, 1);
#define RD_AHI(base)                                                          \
  af[0][0] = LDF(base, ar0 + 64, 0); af[1][0] = LDF(base, ar0 + 80, 0);       \
  af[2][0] = LDF(base, ar0 + 96, 0); af[3][0] = LDF(base, ar0 + 112, 0);      \
  af[0][1] = LDF(base, ar0 + 64, 1); af[1][1] = LDF(base, ar0 + 80, 1);       \
  af[2][1] = LDF(base, ar0 + 96, 1); af[3][1] = LDF(base, ar0 + 112, 1);
#define RD_BLO(base)                                                          \
  bf_lo[0][0] = LDF(base, br0, 0); bf_lo[1][0] = LDF(base, br1, 0);           \
  bf_lo[0][1] = LDF(base, br0, 1); bf_lo[1][1] = LDF(base, br1, 1);
#define RD_BHI(base)                                                          \
  bf_hi[0][0] = LDF(base, br2, 0); bf_hi[1][0] = LDF(base, br3, 0);           \
  bf_hi[0][1] = LDF(base, br2, 1); bf_hi[1][1] = LDF(base, br3, 1);

#define HMFMA(mb, Bf, nb, kkv)                                                \
  _Pragma("unroll") for (int mm = 0; mm < 4; ++mm)                            \
  _Pragma("unroll") for (int nn = 0; nn < 2; ++nn)                            \
    acc[(mb) + mm][(nb) + nn] = __builtin_amdgcn_mfma_f32_16x16x32_bf16(      \
        af[mm][kkv], Bf[nn][kkv], acc[(mb) + mm][(nb) + nn], 0, 0, 0);

#define BARR __builtin_amdgcn_s_barrier()
#define SBARR __builtin_amdgcn_sched_barrier(0)
#define PRIO1 __builtin_amdgcn_s_setprio(1)
#define PRIO0 __builtin_amdgcn_s_setprio(0)
#define VMC8 asm volatile("s_waitcnt vmcnt(8)" ::: "memory")
#define VMC0 asm volatile("s_waitcnt vmcnt(0)" ::: "memory")

// one K-tile: 4 MFMA clusters, inline reads pinned between clusters,
// then the 2-barrier sync block. Pa/Pb = this tile's buf, Qa/Qb = other buf.
// ts = tile index to stage into THIS buf (t+2); reads next tile's q00 frags.
#define TILE_BODY(Pa, Pb, Qa, Qb, ts, bufidx)                                 \
  PRIO1; HMFMA(0, bf_lo, 0, 0); HMFMA(0, bf_lo, 0, 1); PRIO0; SBARR;          \
  RD_BHI(Pb); SBARR;                                                          \
  PRIO1; HMFMA(0, bf_hi, 2, 0); HMFMA(0, bf_hi, 2, 1); PRIO0; SBARR;          \
  RD_AHI(Pa); SBARR;                                                          \
  PRIO1; HMFMA(4, bf_lo, 0, 0); HMFMA(4, bf_lo, 0, 1); PRIO0; SBARR;          \
  PRIO1; HMFMA(4, bf_hi, 2, 0); HMFMA(4, bf_hi, 2, 1); PRIO0;                 \
  BARR;                                                                       \
  if ((ts) < NTK) {                                                           \
    STAGE_A(ts, bufidx, 0); STAGE_A(ts, bufidx, 1);                           \
    STAGE_A(ts, bufidx, 2); STAGE_A(ts, bufidx, 3);                           \
    STAGE_B(ts, bufidx, 0); STAGE_B(ts, bufidx, 1);                           \
    STAGE_B(ts, bufidx, 2); STAGE_B(ts, bufidx, 3);                           \
    VMC8;                                                                     \
  } else if ((ts) - 1 < NTK) { VMC0; }                                        \
  BARR;                                                                       \
  if ((ts) - 1 < NTK) { RD_ALO(Qa); RD_BLO(Qb); }

  v4f acc[8][4];
#pragma unroll
  for (int m = 0; m < 8; ++m)
#pragma unroll
    for (int n = 0; n < 4; ++n)
#pragma unroll
      for (int j = 0; j < 4; ++j) acc[m][n][j] = 0.f;

  const us* B0a = &lds[0];
  const us* B0b = &lds[16384];
  const us* B1a = &lds[32768];
  const us* B1b = &lds[49152];
  const int ar0 = wr * 128 + lr;
  const int br0 = COLREL(0) + lr, br1 = COLREL(1) + lr;
  const int br2 = COLREL(2) + lr, br3 = COLREL(3) + lr;

  // prologue: tile0 -> buf0, tile1 -> buf1; wait tile0 only (8 in flight)
  STAGE_A(0, 0, 0); STAGE_A(0, 0, 1); STAGE_A(0, 0, 2); STAGE_A(0, 0, 3);
  STAGE_B(0, 0, 0); STAGE_B(0, 0, 1); STAGE_B(0, 0, 2); STAGE_B(0, 0, 3);
  STAGE_A(1, 1, 0); STAGE_A(1, 1, 1); STAGE_A(1, 1, 2); STAGE_A(1, 1, 3);
  STAGE_B(1, 1, 0); STAGE_B(1, 1, 1); STAGE_B(1, 1, 2); STAGE_B(1, 1, 3);
  VMC8;
  BARR;

  v8bf af[4][2], bf_lo[2][2], bf_hi[2][2];
  RD_ALO(B0a); RD_BLO(B0b);

  for (int t = 0; t < NTK; t += 2) {
    // tile t (buf0): stage t+2 into buf0; next-tile frags from buf1
    TILE_BODY(B0a, B0b, B1a, B1b, t + 2, 0);
    // tile t+1 (buf1): stage t+3 into buf1; next-tile frags from buf0
    TILE_BODY(B1a, B1b, B0a, B0b, t + 3, 1);
  }
#undef STAGE_A
#undef STAGE_B
#undef TILE_BODY

  if (EPI == 0) {
#pragma unroll
    for (int m = 0; m < 8; ++m) {
#pragma unroll
      for (int r = 0; r < 4; ++r) {
        int row = row0 + wr * 128 + m * 16 + lg * 4 + r;
#pragma unroll
        for (int n = 0; n < 4; ++n) {
          int col = col0 + COLREL(n) + lr;
          outF[(long)row * N + col] = acc[m][n][r];
        }
      }
    }
  } else {
    // fused RoPE epilogue, register-local (partner = frag n^2)
    const int cb = col0 + (wc >> 1) * 128;  // head-block base column
    const int which = cb >> 12;             // 0=Q 1=K 2=V
    const int h = (cb >> 7) & 31;
    us* base = (which == 0) ? outQ : ((which == 1) ? outK : outV);
#pragma unroll
    for (int m = 0; m < 8; ++m) {
#pragma unroll
      for (int r = 0; r < 4; ++r) {
        int trow = row0 + wr * 128 + m * 16 + lg * 4 + r;
        int b2 = trow >> 10, spos = trow & 1023;
        us* rowp = base + ((b2 * 32 + h) * 1024 + spos) * 128;
        if (which < 2) {
#pragma unroll
          for (int n = 0; n < 4; ++n) {
            int dl = (wc & 1) * 32 + (n & 1) * 16 + lr;  // d & 63
            float c = cosT[(long)trow * 64 + dl];
            float s = sinT[(long)trow * 64 + dl];
            float own = acc[m][n][r];
            float other = acc[m][n ^ 2][r];
            float y = (n < 2) ? (own * c - other * s) : (own * c + other * s);
            rowp[(n >> 1) * 64 + dl] = f2bf(y);
          }
        } else {
#pragma unroll
          for (int n = 0; n < 4; ++n) {
            int dl = (wc & 1) * 32 + (n & 1) * 16 + lr;
            rowp[(n >> 1) * 64 + dl] = f2bf(acc[m][n][r]);
          }
        }
      }
    }
  }
}

// ---------------- V transpose: [bh][s][d] -> [bh][d][s] ----------------
__global__ void transpose_v(const us* __restrict__ V, us* __restrict__ Vt) {
  __shared__ us tile[64][66];
  const int tid = threadIdx.x;
  const int s0 = blockIdx.x * 64;
  const int d0 = blockIdx.y * 64;
  const int bh = blockIdx.z;
  const us* Vb = V + (long)bh * 131072;
  us* Vtb = Vt + (long)bh * 131072;
  const int rr = tid >> 2, cq = tid & 3;
  us8v v0 = *(const us8v*)(Vb + (s0 + rr) * 128 + d0 + cq * 16);
  us8v v1 = *(const us8v*)(Vb + (s0 + rr) * 128 + d0 + cq * 16 + 8);
#pragma unroll
  for (int j = 0; j < 8; ++j) {
    tile[rr][cq * 16 + j] = v0[j];
    tile[rr][cq * 16 + 8 + j] = v1[j];
  }
  __syncthreads();
  us8v o0, o1;
#pragma unroll
  for (int j = 0; j < 8; ++j) {
    o0[j] = tile[cq * 16 + j][rr];
    o1[j] = tile[cq * 16 + 8 + j][rr];
  }
  *(us8v*)(Vtb + (d0 + rr) * 1024 + s0 + cq * 16) = o0;
  *(us8v*)(Vtb + (d0 + rr) * 1024 + s0 + cq * 16 + 8) = o1;
}

// ---------------- causal flash attention (R6, unchanged) ----------------
__global__ __launch_bounds__(256, 2) void attn_kernel(
    const us* __restrict__ Q, const us* __restrict__ Kg,
    const us* __restrict__ Vt, us* __restrict__ Out) {
  __shared__ us Ks[2][8192];
  __shared__ us Vs[2][8192];
  __shared__ us Ps[4 * 2048];
  const int tid = threadIdx.x, lane = tid & 63, w = tid >> 6;
  const int bh = blockIdx.y;
  const int lr = lane & 15, lg = lane >> 4;
  const us* Kbase = Kg + (long)bh * 131072;
  const us* Vbase = Vt + (long)bh * 131072;
  us* Pw = &Ps[w * 2048];
  const int b = bh >> 5, h = bh & 31;

#define STAGE_KV(kt, bf)                                                      \
  do {                                                                        \
    _Pragma("unroll") for (int i_ = 0; i_ < 4; ++i_) {                        \
      int c_ = (i_ * 4 + w) * 64 + lane;                                      \
      int rk_ = c_ >> 4, pc_ = c_ & 15;                                       \
      GLD16(Kbase + ((kt) * 64 + rk_) * 128 + ((pc_ ^ (rk_ & 7)) * 8),        \
            &Ks[bf][(i_ * 4 + w) * 512]);                                     \
    }                                                                         \
    _Pragma("unroll") for (int i_ = 0; i_ < 4; ++i_) {                        \
      int c_ = (i_ * 4 + w) * 64 + lane;                                      \
      int dd_ = c_ >> 3, pc_ = c_ & 7;                                        \
      GLD16(Vbase + dd_ * 1024 + (kt) * 64 + ((pc_ ^ (dd_ & 7)) * 8),         \
            &Vs[bf][(i_ * 4 + w) * 512]);                                     \
    }                                                                         \
  } while (0)

#pragma unroll 1
  for (int qsel = 0; qsel < 2; ++qsel) {
    const int qt = qsel ? (int)blockIdx.x : 7 - (int)blockIdx.x;
    const int q0 = qt * 128 + w * 32;

    v8bf qf[2][4];
    const us* Qb = Q + ((long)bh * 1024 + q0) * 128;
#pragma unroll
    for (int mq = 0; mq < 2; ++mq)
#pragma unroll
      for (int ks = 0; ks < 4; ++ks)
        qf[mq][ks] = *(const v8bf*)(Qb + (mq * 16 + lr) * 128 + ks * 32 + lg * 8);

    float m_run[2][4], l_run[2][4];
    v4f o_acc[2][8];
#pragma unroll
    for (int mq = 0; mq < 2; ++mq) {
#pragma unroll
      for (int r = 0; r < 4; ++r) {
        m_run[mq][r] = -1e30f;
        l_run[mq][r] = 0.f;
      }
#pragma unroll
      for (int nd = 0; nd < 8; ++nd)
#pragma unroll
        for (int j = 0; j < 4; ++j) o_acc[mq][nd][j] = 0.f;
    }

    const int nkt = 2 * qt + 2;
    STAGE_KV(0, 0);
    for (int kt = 0; kt < nkt; ++kt) {
      const int cb = kt & 1;
      if (kt + 1 < nkt) {
        STAGE_KV(kt + 1, cb ^ 1);
        asm volatile("s_waitcnt vmcnt(8)" ::: "memory");
      } else {
        asm volatile("s_waitcnt vmcnt(0)" ::: "memory");
      }
      __builtin_amdgcn_s_barrier();

      v4f sacc[2][4];
#pragma unroll
      for (int mq = 0; mq < 2; ++mq)
#pragma unroll
        for (int nk = 0; nk < 4; ++nk)
#pragma unroll
          for (int j = 0; j < 4; ++j) sacc[mq][nk][j] = 0.f;
      __builtin_amdgcn_s_setprio(1);
#pragma unroll
      for (int nk = 0; nk < 4; ++nk) {
        int key = nk * 16 + lr;
#pragma unroll
        for (int ks = 0; ks < 4; ++ks) {
          int pc = (ks * 4 + lg) ^ (key & 7);
          v8bf kf = *(const v8bf*)(&Ks[cb][key * 128 + pc * 8]);
          sacc[0][nk] = __builtin_amdgcn_mfma_f32_16x16x32_bf16(qf[0][ks], kf, sacc[0][nk], 0, 0, 0);
          sacc[1][nk] = __builtin_amdgcn_mfma_f32_16x16x32_bf16(qf[1][ks], kf, sacc[1][nk], 0, 0, 0);
        }
      }
      __builtin_amdgcn_s_setprio(0);

      const bool needMask = (kt * 64 + 63) > q0;
#pragma unroll
      for (int mq = 0; mq < 2; ++mq)
#pragma unroll
        for (int nk = 0; nk < 4; ++nk)
#pragma unroll
          for (int r = 0; r < 4; ++r) {
            float sv = sacc[mq][nk][r] * SCALE;
            if (needMask && (kt * 64 + nk * 16 + lr) > (q0 + mq * 16 + lg * 4 + r)) sv = -1e30f;
            sacc[mq][nk][r] = sv;
          }

      float pm[2][4];
      float need = 0.f;
#pragma unroll
      for (int mq = 0; mq < 2; ++mq)
#pragma unroll
        for (int r = 0; r < 4; ++r) {
          float p = fmaxf(fmaxf(sacc[mq][0][r], sacc[mq][1][r]),
                          fmaxf(sacc[mq][2][r], sacc[mq][3][r]));
          p = fmaxf(p, __shfl_xor(p, 1));
          p = fmaxf(p, __shfl_xor(p, 2));
          p = fmaxf(p, __shfl_xor(p, 4));
          p = fmaxf(p, __shfl_xor(p, 8));
          pm[mq][r] = p;
          need = fmaxf(need, p - m_run[mq][r]);
        }
      if (__any(need > 8.f)) {
#pragma unroll
        for (int mq = 0; mq < 2; ++mq)
#pragma unroll
          for (int r = 0; r < 4; ++r) {
            float mnew = fmaxf(m_run[mq][r], pm[mq][r]);
            float alpha = __expf(m_run[mq][r] - mnew);
            m_run[mq][r] = mnew;
            l_run[mq][r] *= alpha;
#pragma unroll
            for (int nd = 0; nd < 8; ++nd)
#pragma unroll
              for (int j = 0; j < 4; ++j) o_acc[mq][nd][j] = (j == r) ? o_acc[mq][nd][j] * alpha : o_acc[mq][nd][j];
          }
      }

      float rsum[2][4];
#pragma unroll
      for (int mq = 0; mq < 2; ++mq)
#pragma unroll
        for (int r = 0; r < 4; ++r) rsum[mq][r] = 0.f;
#pragma unroll
      for (int mq = 0; mq < 2; ++mq)
#pragma unroll
        for (int nk = 0; nk < 4; ++nk) {
          int key = nk * 16 + lr;
#pragma unroll
          for (int r = 0; r < 4; ++r) {
            float p = __expf(sacc[mq][nk][r] - m_run[mq][r]);
            rsum[mq][r] += p;
            int qrow = mq * 16 + lg * 4 + r;
            int pcw = (key >> 3) ^ (qrow & 7);
            Pw[qrow * 64 + pcw * 8 + (key & 7)] = f2bf(p);
          }
        }

#pragma unroll
      for (int mq = 0; mq < 2; ++mq)
#pragma unroll
        for (int r = 0; r < 4; ++r) {
          float rs = rsum[mq][r];
          rs += __shfl_xor(rs, 1);
          rs += __shfl_xor(rs, 2);
          rs += __shfl_xor(rs, 4);
          rs += __shfl_xor(rs, 8);
          l_run[mq][r] += rs;
        }

      __builtin_amdgcn_s_setprio(1);
#pragma unroll
      for (int kk = 0; kk < 2; ++kk) {
        v8bf pa[2];
#pragma unroll
        for (int mq = 0; mq < 2; ++mq) {
          int q = mq * 16 + lr;
          int pc = (kk * 4 + lg) ^ (q & 7);
          pa[mq] = *(const v8bf*)(&Pw[q * 64 + pc * 8]);
        }
#pragma unroll
        for (int nd = 0; nd < 8; ++nd) {
          int d = nd * 16 + lr;
          int pc = (kk * 4 + lg) ^ (d & 7);
          v8bf vb = *(const v8bf*)(&Vs[cb][d * 64 + pc * 8]);
          o_acc[0][nd] = __builtin_amdgcn_mfma_f32_16x16x32_bf16(pa[0], vb, o_acc[0][nd], 0, 0, 0);
          o_acc[1][nd] = __builtin_amdgcn_mfma_f32_16x16x32_bf16(pa[1], vb, o_acc[1][nd], 0, 0, 0);
        }
      }
      __builtin_amdgcn_s_setprio(0);
      __builtin_amdgcn_s_barrier();
    }

#pragma unroll
    for (int mq = 0; mq < 2; ++mq)
#pragma unroll
      for (int r = 0; r < 4; ++r) {
        int srow = q0 + mq * 16 + lg * 4 + r;
        float inv = 1.f / l_run[mq][r];
        us* orow = Out + ((long)b * 1024 + srow) * 4096 + h * 128;
#pragma unroll
        for (int nd = 0; nd < 8; ++nd) orow[nd * 16 + lr] = f2bf(o_acc[mq][nd][r] * inv);
      }
  }
#undef STAGE_KV
}

// ---------------- launcher ----------------
// ws layout (bytes), peak 224 MB with reuse:
//  [0,   32M)  hidden_bf16  -> reused as Vt after QKV GEMM
//  [32M, 128M) wqkv_bf16    -> reused as attn_bf16 [32M,64M) + wo_bf16 [64M,96M)
//  [128M,160M) Q  [160M,192M) K  [192M,224M) V     (all [b][h][s][d])
extern "C" void kernel_launch(void* const* d_in, const int* in_sizes, int n_in,
                              void* d_out, int out_size, void* d_ws, size_t ws_size,
                              hipStream_t stream) {
  const float* hidden = (const float*)d_in[0];
  const float* cosT = (const float*)d_in[1];
  const float* sinT = (const float*)d_in[2];
  const float* wqkv = (const float*)d_in[3];
  const float* wo = (const float*)d_in[4];
  float* out = (float*)d_out;
  char* ws = (char*)d_ws;

  us* hB = (us*)(ws);
  us* wqB = (us*)(ws + 33554432ull);
  us* Qb = (us*)(ws + 134217728ull);
  us* Kb = (us*)(ws + 167772160ull);
  us* Vb = (us*)(ws + 201326592ull);
  us* VtB = (us*)(ws);                  // reuse hidden_bf16 region
  us* atB = (us*)(ws + 33554432ull);    // reuse wqkv_bf16 region
  us* woB = (us*)(ws + 67108864ull);    // reuse wqkv_bf16 region (2nd third)

  cast2_kernel<<<2048, 256, 0, stream>>>(hidden, hB, 4096 * 4096,
                                         wqkv, wqB, 12288 * 4096);
  gemm8<1><<<768, 512, 0, stream>>>(hB, wqB, 4096, 12288, 4096,
                                    nullptr, Qb, Kb, Vb, cosT, sinT, 16);
  transpose_v<<<dim3(16, 2, 128), 256, 0, stream>>>(Vb, VtB);
  cast_kernel<<<2048, 256, 0, stream>>>(wo, woB, 4096 * 4096);
  attn_kernel<<<dim3(4, 128), 256, 0, stream>>>(Qb, Kb, VtB, atB);
  gemm8<0><<<256, 512, 0, stream>>>(atB, woB, 4096, 4096, 4096,
                                    out, nullptr, nullptr, nullptr, nullptr, nullptr, 16);
}

// Round 9
// 658.160 us; speedup vs baseline: 1.1861x; 1.1861x over previous
//
#include <hip/hip_runtime.h>

typedef unsigned short us;
typedef __bf16 v8bf __attribute__((ext_vector_type(8)));
typedef float v4f __attribute__((ext_vector_type(4)));
typedef us us4v __attribute__((ext_vector_type(4)));
typedef us us8v __attribute__((ext_vector_type(8)));
typedef float f4v __attribute__((ext_vector_type(4)));

#define SCALE 0.08838834764831845f

__device__ __forceinline__ us f2bf(float f) {
  unsigned u = __builtin_bit_cast(unsigned, f);
  u += 0x7fffu + ((u >> 16) & 1u);
  return (us)(u >> 16);
}
__device__ __forceinline__ float bf2f(us h) {
  unsigned u = ((unsigned)h) << 16;
  return __builtin_bit_cast(float, u);
}

typedef const __attribute__((address_space(1))) void* gas_t;
typedef __attribute__((address_space(3))) void* las_t;
#define GLD16(gp, lp) __builtin_amdgcn_global_load_lds((gas_t)(gp), (las_t)(lp), 16, 0, 0)

// ---------------- fp32 -> bf16 casts ----------------
__global__ void cast_kernel(const float* __restrict__ in, us* __restrict__ out, int n) {
  int stride = gridDim.x * blockDim.x * 4;
  for (int i = (blockIdx.x * blockDim.x + threadIdx.x) * 4; i < n; i += stride) {
    f4v f = *(const f4v*)(in + i);
    us4v o;
#pragma unroll
    for (int j = 0; j < 4; ++j) o[j] = f2bf(f[j]);
    *(us4v*)(out + i) = o;
  }
}

__global__ void cast2_kernel(const float* __restrict__ a, us* __restrict__ oa, int na,
                             const float* __restrict__ b, us* __restrict__ ob, int nb) {
  int total = na + nb;
  int stride = gridDim.x * blockDim.x * 4;
  for (int i = (blockIdx.x * blockDim.x + threadIdx.x) * 4; i < total; i += stride) {
    const float* s = (i < na) ? (a + i) : (b + (i - na));
    us* d = (i < na) ? (oa + i) : (ob + (i - na));
    f4v f = *(const f4v*)s;
    us4v o;
#pragma unroll
    for (int j = 0; j < 4; ++j) o[j] = f2bf(f[j]);
    *(us4v*)d = o;
  }
}

// ---------------- 256x256 GEMM, 8-phase lockstep + 1-phase read lookahead ----
// R9: identical dataflow to R5/R7 (same reads/stages/barriers/vmcnt), but
// ds_reads are rotated to AFTER the MFMA cluster within each phase: phase =
// {lgkm(0); setprio; MFMA(frags read LAST phase); reads-for-next-quadrant;
//  2xGLD stage; [vmcnt]; s_barrier}. Reads are serviced by the LDS pipe
// concurrently with the MFMA cluster + barrier convergence, so the post-
// barrier lgkm(0) is ~free (was: ~750cyc serial read-drain per phase).
// Read schedule per tile: ph0->B-hi(4), ph1->A-hi(8), ph2->none,
// ph3->next tile's q00 (12; valid: VMC4 at ph3 drains that buffer's loads).
template <int EPI>
__global__ __launch_bounds__(512, 2) void gemm8(
    const us* __restrict__ A, const us* __restrict__ Bt, int M, int N, int K,
    float* __restrict__ outF, us* __restrict__ outQ, us* __restrict__ outK,
    us* __restrict__ outV, const float* __restrict__ cosT,
    const float* __restrict__ sinT, int MT) {
  __shared__ us lds[65536];  // buf0: A[0,16384) B[16384,32768); buf1: +32768
  const int tid = threadIdx.x, lane = tid & 63, w = tid >> 6;
  const int nwg = gridDim.x;
  const int bid = blockIdx.x;
  const int cpx = nwg >> 3;
  const int swz = (bid & 7) * cpx + (bid >> 3);  // grids %8==0 (768, 256)
  const int bm = swz % MT, bn = swz / MT;
  const int row0 = bm * 256, col0 = bn * 256;
  const int wr = w >> 2, wc = w & 3;
  const int lr = lane & 15, lg = lane >> 4;
  const int NTK = K >> 6;  // even (64)

#define STAGE_A(t, p, j)                                                      \
  do {                                                                        \
    int q_ = (j) * 512 + tid;                                                 \
    int row_ = q_ >> 3, cph_ = q_ & 7;                                        \
    GLD16(A + (long)(row0 + row_) * K + (t) * 64 + ((cph_ ^ (row_ & 7)) * 8), \
          &lds[(p) * 32768 + ((j) * 512 + w * 64) * 8]);                      \
  } while (0)
#define STAGE_B(t, p, j)                                                      \
  do {                                                                        \
    int q_ = (j) * 512 + tid;                                                 \
    int row_ = q_ >> 3, cph_ = q_ & 7;                                        \
    GLD16(Bt + (long)(col0 + row_) * K + (t) * 64 + ((cph_ ^ (row_ & 7)) * 8),\
          &lds[(p) * 32768 + 16384 + ((j) * 512 + w * 64) * 8]);              \
  } while (0)

  // wave fragment n -> B-row / C-col remap (RoPE partner d<->d+64 = n^2)
#define COLREL(n) (((wc) >> 1) * 128 + ((n) >> 1) * 64 + ((wc) & 1) * 32 + ((n) & 1) * 16)

// swizzled fragment load (row&7 == lr&7 for all rows we touch)
#define LDF(base, row, kkv) \
  (*(const v8bf*)&(base)[(row) * 64 + (((((kkv) * 4) + lg) ^ ((row) & 7)) * 8)])

#define RD_ALO(base)                                                          \
  af[0][0] = LDF(base, ar0, 0); af[1][0] = LDF(base, ar0 + 16, 0);            \
  af[2][0] = LDF(base, ar0 + 32, 0); af[3][0] = LDF(base, ar0 + 48, 0);       \
  af[0][1] = LDF(base, ar0, 1); af[1][1] = LDF(base, ar0 + 16, 1);            \
  af[2][1] = LDF(base, ar0 + 32, 1); af[3][1] = LDF(base, ar0 + 48, 1);
#define RD_AHI(base)                                                          \
  af[0][0] = LDF(base, ar0 + 64, 0); af[1][0] = LDF(base, ar0 + 80, 0);       \
  af[2][0] = LDF(base, ar0 + 96, 0); af[3][0] = LDF(base, ar0 + 112, 0);      \
  af[0][1] = LDF(base, ar0 + 64, 1); af[1][1] = LDF(base, ar0 + 80, 1);       \
  af[2][1] = LDF(base, ar0 + 96, 1); af[3][1] = LDF(base, ar0 + 112, 1);
#define RD_BLO(base)                                                          \
  bf_lo[0][0] = LDF(base, br0, 0); bf_lo[1][0] = LDF(base, br1, 0);           \
  bf_lo[0][1] = LDF(base, br0, 1); bf_lo[1][1] = LDF(base, br1, 1);
#define RD_BHI(base)                                                          \
  bf_hi[0][0] = LDF(base, br2, 0); bf_hi[1][0] = LDF(base, br3, 0);           \
  bf_hi[0][1] = LDF(base, br2, 1); bf_hi[1][1] = LDF(base, br3, 1);

#define HMFMA(mb, Bf, nb, kkv)                                                \
  _Pragma("unroll") for (int mm = 0; mm < 4; ++mm)                            \
  _Pragma("unroll") for (int nn = 0; nn < 2; ++nn)                            \
    acc[(mb) + mm][(nb) + nn] = __builtin_amdgcn_mfma_f32_16x16x32_bf16(      \
        af[mm][kkv], Bf[nn][kkv], acc[(mb) + mm][(nb) + nn], 0, 0, 0);

#define BARR __builtin_amdgcn_s_barrier()
#define LGKM0 asm volatile("s_waitcnt lgkmcnt(0)" ::: "memory")
#define PRIO1 __builtin_amdgcn_s_setprio(1)
#define PRIO0 __builtin_amdgcn_s_setprio(0)
#define VMC4 asm volatile("s_waitcnt vmcnt(4)" ::: "memory")
#define VMC0 asm volatile("s_waitcnt vmcnt(0)" ::: "memory")

  v4f acc[8][4];
#pragma unroll
  for (int m = 0; m < 8; ++m)
#pragma unroll
    for (int n = 0; n < 4; ++n)
#pragma unroll
      for (int j = 0; j < 4; ++j) acc[m][n][j] = 0.f;

  const us* B0a = &lds[0];
  const us* B0b = &lds[16384];
  const us* B1a = &lds[32768];
  const us* B1b = &lds[49152];
  const int ar0 = wr * 128 + lr;
  const int br0 = COLREL(0) + lr, br1 = COLREL(1) + lr;
  const int br2 = COLREL(2) + lr, br3 = COLREL(3) + lr;

  // prologue: A(0),B(0) -> buf0; B(1) -> buf1 (R5 plan); drain tile0 (leave
  // B(1)'s 4 in flight), barrier, pre-read tile0's q00 frags.
  STAGE_A(0, 0, 0); STAGE_A(0, 0, 1); STAGE_A(0, 0, 2); STAGE_A(0, 0, 3);
  STAGE_B(0, 0, 0); STAGE_B(0, 0, 1); STAGE_B(0, 0, 2); STAGE_B(0, 0, 3);
  STAGE_B(1, 1, 0); STAGE_B(1, 1, 1); STAGE_B(1, 1, 2); STAGE_B(1, 1, 3);
  VMC4;
  BARR;

  v8bf af[4][2], bf_lo[2][2], bf_hi[2][2];
  RD_ALO(B0a); RD_BLO(B0b);

  for (int t = 0; t < NTK; t += 2) {
    // ================= tile t (buf0) =================
    // ph0: MFMA q00 | read B-hi | stage A(t+1) j0,j1
    LGKM0; PRIO1; HMFMA(0, bf_lo, 0, 0); HMFMA(0, bf_lo, 0, 1); PRIO0;
    RD_BHI(B0b);
    STAGE_A(t + 1, 1, 0); STAGE_A(t + 1, 1, 1);
    BARR;
    // ph1: MFMA q01 | read A-hi | stage A(t+1) j2,j3
    LGKM0; PRIO1; HMFMA(0, bf_hi, 2, 0); HMFMA(0, bf_hi, 2, 1); PRIO0;
    RD_AHI(B0a);
    STAGE_A(t + 1, 1, 2); STAGE_A(t + 1, 1, 3);
    BARR;
    // ph2: MFMA q10 | no reads | stage B(t+2) j0,j1
    LGKM0; PRIO1; HMFMA(4, bf_lo, 0, 0); HMFMA(4, bf_lo, 0, 1); PRIO0;
    if (t + 2 < NTK) { STAGE_B(t + 2, 0, 0); STAGE_B(t + 2, 0, 1); }
    BARR;
    // ph3: MFMA q11 | stage B(t+2) j2,j3 | VMC4 (drains A(t+1),B(t+1);
    //      leaves B(t+2) in flight) | read tile t+1's q00 (buf1)
    LGKM0; PRIO1; HMFMA(4, bf_hi, 2, 0); HMFMA(4, bf_hi, 2, 1); PRIO0;
    if (t + 2 < NTK) { STAGE_B(t + 2, 0, 2); STAGE_B(t + 2, 0, 3); VMC4; }
    else { VMC0; }
    RD_ALO(B1a); RD_BLO(B1b);
    BARR;
    // ================= tile t+1 (buf1) =================
    // ph4: MFMA q00 | read B-hi | stage A(t+2) j0,j1
    LGKM0; PRIO1; HMFMA(0, bf_lo, 0, 0); HMFMA(0, bf_lo, 0, 1); PRIO0;
    RD_BHI(B1b);
    if (t + 2 < NTK) { STAGE_A(t + 2, 0, 0); STAGE_A(t + 2, 0, 1); }
    BARR;
    // ph5: MFMA q01 | read A-hi | stage A(t+2) j2,j3
    LGKM0; PRIO1; HMFMA(0, bf_hi, 2, 0); HMFMA(0, bf_hi, 2, 1); PRIO0;
    RD_AHI(B1a);
    if (t + 2 < NTK) { STAGE_A(t + 2, 0, 2); STAGE_A(t + 2, 0, 3); }
    BARR;
    // ph6: MFMA q10 | no reads | stage B(t+3) j0,j1
    LGKM0; PRIO1; HMFMA(4, bf_lo, 0, 0); HMFMA(4, bf_lo, 0, 1); PRIO0;
    if (t + 3 < NTK) { STAGE_B(t + 3, 1, 0); STAGE_B(t + 3, 1, 1); }
    BARR;
    // ph7: MFMA q11 | stage B(t+3) j2,j3 | VMC4 | read tile t+2's q00 (buf0)
    LGKM0; PRIO1; HMFMA(4, bf_hi, 2, 0); HMFMA(4, bf_hi, 2, 1); PRIO0;
    if (t + 3 < NTK) { STAGE_B(t + 3, 1, 2); STAGE_B(t + 3, 1, 3); VMC4; }
    else if (t + 2 < NTK) { VMC0; }
    if (t + 2 < NTK) { RD_ALO(B0a); RD_BLO(B0b); }
    BARR;
  }
#undef STAGE_A
#undef STAGE_B

  if (EPI == 0) {
#pragma unroll
    for (int m = 0; m < 8; ++m) {
#pragma unroll
      for (int r = 0; r < 4; ++r) {
        int row = row0 + wr * 128 + m * 16 + lg * 4 + r;
#pragma unroll
        for (int n = 0; n < 4; ++n) {
          int col = col0 + COLREL(n) + lr;
          outF[(long)row * N + col] = acc[m][n][r];
        }
      }
    }
  } else {
    // fused RoPE epilogue, register-local (partner = frag n^2)
    const int cb = col0 + (wc >> 1) * 128;  // head-block base column
    const int which = cb >> 12;             // 0=Q 1=K 2=V
    const int h = (cb >> 7) & 31;
    us* base = (which == 0) ? outQ : ((which == 1) ? outK : outV);
#pragma unroll
    for (int m = 0; m < 8; ++m) {
#pragma unroll
      for (int r = 0; r < 4; ++r) {
        int trow = row0 + wr * 128 + m * 16 + lg * 4 + r;
        int b2 = trow >> 10, spos = trow & 1023;
        us* rowp = base + ((b2 * 32 + h) * 1024 + spos) * 128;
        if (which < 2) {
#pragma unroll
          for (int n = 0; n < 4; ++n) {
            int dl = (wc & 1) * 32 + (n & 1) * 16 + lr;  // d & 63
            float c = cosT[(long)trow * 64 + dl];
            float s = sinT[(long)trow * 64 + dl];
            float own = acc[m][n][r];
            float other = acc[m][n ^ 2][r];
            float y = (n < 2) ? (own * c - other * s) : (own * c + other * s);
            rowp[(n >> 1) * 64 + dl] = f2bf(y);
          }
        } else {
#pragma unroll
          for (int n = 0; n < 4; ++n) {
            int dl = (wc & 1) * 32 + (n & 1) * 16 + lr;
            rowp[(n >> 1) * 64 + dl] = f2bf(acc[m][n][r]);
          }
        }
      }
    }
  }
}

// ---------------- V transpose: [bh][s][d] -> [bh][d][s] ----------------
__global__ void transpose_v(const us* __restrict__ V, us* __restrict__ Vt) {
  __shared__ us tile[64][66];
  const int tid = threadIdx.x;
  const int s0 = blockIdx.x * 64;
  const int d0 = blockIdx.y * 64;
  const int bh = blockIdx.z;
  const us* Vb = V + (long)bh * 131072;
  us* Vtb = Vt + (long)bh * 131072;
  const int rr = tid >> 2, cq = tid & 3;
  us8v v0 = *(const us8v*)(Vb + (s0 + rr) * 128 + d0 + cq * 16);
  us8v v1 = *(const us8v*)(Vb + (s0 + rr) * 128 + d0 + cq * 16 + 8);
#pragma unroll
  for (int j = 0; j < 8; ++j) {
    tile[rr][cq * 16 + j] = v0[j];
    tile[rr][cq * 16 + 8 + j] = v1[j];
  }
  __syncthreads();
  us8v o0, o1;
#pragma unroll
  for (int j = 0; j < 8; ++j) {
    o0[j] = tile[cq * 16 + j][rr];
    o1[j] = tile[cq * 16 + 8 + j][rr];
  }
  *(us8v*)(Vtb + (d0 + rr) * 1024 + s0 + cq * 16) = o0;
  *(us8v*)(Vtb + (d0 + rr) * 1024 + s0 + cq * 16 + 8) = o1;
}

// ---------------- causal flash attention (R6, unchanged) ----------------
__global__ __launch_bounds__(256, 2) void attn_kernel(
    const us* __restrict__ Q, const us* __restrict__ Kg,
    const us* __restrict__ Vt, us* __restrict__ Out) {
  __shared__ us Ks[2][8192];
  __shared__ us Vs[2][8192];
  __shared__ us Ps[4 * 2048];
  const int tid = threadIdx.x, lane = tid & 63, w = tid >> 6;
  const int bh = blockIdx.y;
  const int lr = lane & 15, lg = lane >> 4;
  const us* Kbase = Kg + (long)bh * 131072;
  const us* Vbase = Vt + (long)bh * 131072;
  us* Pw = &Ps[w * 2048];
  const int b = bh >> 5, h = bh & 31;

#define STAGE_KV(kt, bf)                                                      \
  do {                                                                        \
    _Pragma("unroll") for (int i_ = 0; i_ < 4; ++i_) {                        \
      int c_ = (i_ * 4 + w) * 64 + lane;                                      \
      int rk_ = c_ >> 4, pc_ = c_ & 15;                                       \
      GLD16(Kbase + ((kt) * 64 + rk_) * 128 + ((pc_ ^ (rk_ & 7)) * 8),        \
            &Ks[bf][(i_ * 4 + w) * 512]);                                     \
    }                                                                         \
    _Pragma("unroll") for (int i_ = 0; i_ < 4; ++i_) {                        \
      int c_ = (i_ * 4 + w) * 64 + lane;                                      \
      int dd_ = c_ >> 3, pc_ = c_ & 7;                                        \
      GLD16(Vbase + dd_ * 1024 + (kt) * 64 + ((pc_ ^ (dd_ & 7)) * 8),         \
            &Vs[bf][(i_ * 4 + w) * 512]);                                     \
    }                                                                         \
  } while (0)

#pragma unroll 1
  for (int qsel = 0; qsel < 2; ++qsel) {
    const int qt = qsel ? (int)blockIdx.x : 7 - (int)blockIdx.x;
    const int q0 = qt * 128 + w * 32;

    v8bf qf[2][4];
    const us* Qb = Q + ((long)bh * 1024 + q0) * 128;
#pragma unroll
    for (int mq = 0; mq < 2; ++mq)
#pragma unroll
      for (int ks = 0; ks < 4; ++ks)
        qf[mq][ks] = *(const v8bf*)(Qb + (mq * 16 + lr) * 128 + ks * 32 + lg * 8);

    float m_run[2][4], l_run[2][4];
    v4f o_acc[2][8];
#pragma unroll
    for (int mq = 0; mq < 2; ++mq) {
#pragma unroll
      for (int r = 0; r < 4; ++r) {
        m_run[mq][r] = -1e30f;
        l_run[mq][r] = 0.f;
      }
#pragma unroll
      for (int nd = 0; nd < 8; ++nd)
#pragma unroll
        for (int j = 0; j < 4; ++j) o_acc[mq][nd][j] = 0.f;
    }

    const int nkt = 2 * qt + 2;
    STAGE_KV(0, 0);
    for (int kt = 0; kt < nkt; ++kt) {
      const int cb = kt & 1;
      if (kt + 1 < nkt) {
        STAGE_KV(kt + 1, cb ^ 1);
        asm volatile("s_waitcnt vmcnt(8)" ::: "memory");
      } else {
        asm volatile("s_waitcnt vmcnt(0)" ::: "memory");
      }
      __builtin_amdgcn_s_barrier();

      v4f sacc[2][4];
#pragma unroll
      for (int mq = 0; mq < 2; ++mq)
#pragma unroll
        for (int nk = 0; nk < 4; ++nk)
#pragma unroll
          for (int j = 0; j < 4; ++j) sacc[mq][nk][j] = 0.f;
      __builtin_amdgcn_s_setprio(1);
#pragma unroll
      for (int nk = 0; nk < 4; ++nk) {
        int key = nk * 16 + lr;
#pragma unroll
        for (int ks = 0; ks < 4; ++ks) {
          int pc = (ks * 4 + lg) ^ (key & 7);
          v8bf kf = *(const v8bf*)(&Ks[cb][key * 128 + pc * 8]);
          sacc[0][nk] = __builtin_amdgcn_mfma_f32_16x16x32_bf16(qf[0][ks], kf, sacc[0][nk], 0, 0, 0);
          sacc[1][nk] = __builtin_amdgcn_mfma_f32_16x16x32_bf16(qf[1][ks], kf, sacc[1][nk], 0, 0, 0);
        }
      }
      __builtin_amdgcn_s_setprio(0);

      const bool needMask = (kt * 64 + 63) > q0;
#pragma unroll
      for (int mq = 0; mq < 2; ++mq)
#pragma unroll
        for (int nk = 0; nk < 4; ++nk)
#pragma unroll
          for (int r = 0; r < 4; ++r) {
            float sv = sacc[mq][nk][r] * SCALE;
            if (needMask && (kt * 64 + nk * 16 + lr) > (q0 + mq * 16 + lg * 4 + r)) sv = -1e30f;
            sacc[mq][nk][r] = sv;
          }

      float pm[2][4];
      float need = 0.f;
#pragma unroll
      for (int mq = 0; mq < 2; ++mq)
#pragma unroll
        for (int r = 0; r < 4; ++r) {
          float p = fmaxf(fmaxf(sacc[mq][0][r], sacc[mq][1][r]),
                          fmaxf(sacc[mq][2][r], sacc[mq][3][r]));
          p = fmaxf(p, __shfl_xor(p, 1));
          p = fmaxf(p, __shfl_xor(p, 2));
          p = fmaxf(p, __shfl_xor(p, 4));
          p = fmaxf(p, __shfl_xor(p, 8));
          pm[mq][r] = p;
          need = fmaxf(need, p - m_run[mq][r]);
        }
      if (__any(need > 8.f)) {
#pragma unroll
        for (int mq = 0; mq < 2; ++mq)
#pragma unroll
          for (int r = 0; r < 4; ++r) {
            float mnew = fmaxf(m_run[mq][r], pm[mq][r]);
            float alpha = __expf(m_run[mq][r] - mnew);
            m_run[mq][r] = mnew;
            l_run[mq][r] *= alpha;
#pragma unroll
            for (int nd = 0; nd < 8; ++nd)
#pragma unroll
              for (int j = 0; j < 4; ++j) o_acc[mq][nd][j] = (j == r) ? o_acc[mq][nd][j] * alpha : o_acc[mq][nd][j];
          }
      }

      float rsum[2][4];
#pragma unroll
      for (int mq = 0; mq < 2; ++mq)
#pragma unroll
        for (int r = 0; r < 4; ++r) rsum[mq][r] = 0.f;
#pragma unroll
      for (int mq = 0; mq < 2; ++mq)
#pragma unroll
        for (int nk = 0; nk < 4; ++nk) {
          int key = nk * 16 + lr;
#pragma unroll
          for (int r = 0; r < 4; ++r) {
            float p = __expf(sacc[mq][nk][r] - m_run[mq][r]);
            rsum[mq][r] += p;
            int qrow = mq * 16 + lg * 4 + r;
            int pcw = (key >> 3) ^ (qrow & 7);
            Pw[qrow * 64 + pcw * 8 + (key & 7)] = f2bf(p);
          }
        }

#pragma unroll
      for (int mq = 0; mq < 2; ++mq)
#pragma unroll
        for (int r = 0; r < 4; ++r) {
          float rs = rsum[mq][r];
          rs += __shfl_xor(rs, 1);
          rs += __shfl_xor(rs, 2);
          rs += __shfl_xor(rs, 4);
          rs += __shfl_xor(rs, 8);
          l_run[mq][r] += rs;
        }

      __builtin_amdgcn_s_setprio(1);
#pragma unroll
      for (int kk = 0; kk < 2; ++kk) {
        v8bf pa[2];
#pragma unroll
        for (int mq = 0; mq < 2; ++mq) {
          int q = mq * 16 + lr;
          int pc = (kk * 4 + lg) ^ (q & 7);
          pa[mq] = *(const v8bf*)(&Pw[q * 64 + pc * 8]);
        }
#pragma unroll
        for (int nd = 0; nd < 8; ++nd) {
          int d = nd * 16 + lr;
          int pc = (kk * 4 + lg) ^ (d & 7);
          v8bf vb = *(const v8bf*)(&Vs[cb][d * 64 + pc * 8]);
          o_acc[0][nd] = __builtin_amdgcn_mfma_f32_16x16x32_bf16(pa[0], vb, o_acc[0][nd], 0, 0, 0);
          o_acc[1][nd] = __builtin_amdgcn_mfma_f32_16x16x32_bf16(pa[1], vb, o_acc[1][nd], 0, 0, 0);
        }
      }
      __builtin_amdgcn_s_setprio(0);
      __builtin_amdgcn_s_barrier();
    }

#pragma unroll
    for (int mq = 0; mq < 2; ++mq)
#pragma unroll
      for (int r = 0; r < 4; ++r) {
        int srow = q0 + mq * 16 + lg * 4 + r;
        float inv = 1.f / l_run[mq][r];
        us* orow = Out + ((long)b * 1024 + srow) * 4096 + h * 128;
#pragma unroll
        for (int nd = 0; nd < 8; ++nd) orow[nd * 16 + lr] = f2bf(o_acc[mq][nd][r] * inv);
      }
  }
#undef STAGE_KV
}

// ---------------- launcher ----------------
// ws layout (bytes), peak 224 MB with reuse:
//  [0,   32M)  hidden_bf16  -> reused as Vt after QKV GEMM
//  [32M, 128M) wqkv_bf16    -> reused as attn_bf16 [32M,64M) + wo_bf16 [64M,96M)
//  [128M,160M) Q  [160M,192M) K  [192M,224M) V     (all [b][h][s][d])
extern "C" void kernel_launch(void* const* d_in, const int* in_sizes, int n_in,
                              void* d_out, int out_size, void* d_ws, size_t ws_size,
                              hipStream_t stream) {
  const float* hidden = (const float*)d_in[0];
  const float* cosT = (const float*)d_in[1];
  const float* sinT = (const float*)d_in[2];
  const float* wqkv = (const float*)d_in[3];
  const float* wo = (const float*)d_in[4];
  float* out = (float*)d_out;
  char* ws = (char*)d_ws;

  us* hB = (us*)(ws);
  us* wqB = (us*)(ws + 33554432ull);
  us* Qb = (us*)(ws + 134217728ull);
  us* Kb = (us*)(ws + 167772160ull);
  us* Vb = (us*)(ws + 201326592ull);
  us* VtB = (us*)(ws);                  // reuse hidden_bf16 region
  us* atB = (us*)(ws + 33554432ull);    // reuse wqkv_bf16 region
  us* woB = (us*)(ws + 67108864ull);    // reuse wqkv_bf16 region (2nd third)

  cast2_kernel<<<2048, 256, 0, stream>>>(hidden, hB, 4096 * 4096,
                                         wqkv, wqB, 12288 * 4096);
  gemm8<1><<<768, 512, 0, stream>>>(hB, wqB, 4096, 12288, 4096,
                                    nullptr, Qb, Kb, Vb, cosT, sinT, 16);
  transpose_v<<<dim3(16, 2, 128), 256, 0, stream>>>(Vb, VtB);
  cast_kernel<<<2048, 256, 0, stream>>>(wo, woB, 4096 * 4096);
  attn_kernel<<<dim3(4, 128), 256, 0, stream>>>(Qb, Kb, VtB, atB);
  gemm8<0><<<256, 512, 0, stream>>>(atB, woB, 4096, 4096, 4096,
                                    out, nullptr, nullptr, nullptr, nullptr, nullptr, 16);
}